// Round 10
// baseline (251.062 us; speedup 1.0000x reference)
//
#include <hip/hip_runtime.h>
#include <cfloat>

#define NROWS  32768
#define NCODES 8192
#define DDIM   256
#define KG     4                 // code-split; grid = 256 row-tiles * 4 = 1024 blocks
#define CPB    (NCODES / KG)     // 2048 codes per block
#define CT     32                // codes per stage (16 KB tile), double-buffered
#define TPB    (CPB / CT)        // 64 stages per block
#define RPB    128               // rows per block (2 waves x 64 rows)

typedef __attribute__((ext_vector_type(8)))  __bf16 bf16x8;
typedef __attribute__((ext_vector_type(16))) float  f32x16;

// ---- kernel A: codebook fp32 -> bf16 + fused esq (+1.0 bias for key-packing) ----
// esq' = ||e||^2 + 1 puts MFMA score s = esq' - 2 z.e in ~[0.4, 1.7]:
// strictly positive floats compare monotonically as u32 -> packed
// (score|index) argmin key in kernel B.
__global__ __launch_bounds__(256)
void cvt_cb(const float* __restrict__ cb, __bf16* __restrict__ cbb,
            float* __restrict__ esq) {
    const size_t i = (size_t)(blockIdx.x * 256 + threadIdx.x) * 8;
    const float4 f0 = *(const float4*)(cb + i);
    const float4 f1 = *(const float4*)(cb + i + 4);
    bf16x8 v;
    v[0] = (__bf16)f0.x; v[1] = (__bf16)f0.y; v[2] = (__bf16)f0.z; v[3] = (__bf16)f0.w;
    v[4] = (__bf16)f1.x; v[5] = (__bf16)f1.y; v[6] = (__bf16)f1.z; v[7] = (__bf16)f1.w;
    *(bf16x8*)(cbb + i) = v;
    float s = f0.x * f0.x + f0.y * f0.y + f0.z * f0.z + f0.w * f0.w
            + f1.x * f1.x + f1.y * f1.y + f1.z * f1.z + f1.w * f1.w;
    for (int o = 16; o > 0; o >>= 1) s += __shfl_down(s, o, 32);
    if ((threadIdx.x & 31) == 0) esq[i >> 8] = s + 1.0f;
}

// ---- kernel B: 2-wave barrier domains (anti-phase-lock) ----
// Post-mortem R9: spill fixed; MFMA 41% + VALU 20% + LDS ~7% leaves ~30%
// idle. Theory: per-stage __syncthreads phase-locks the block's 4 waves --
// all enter MFMA together (pipe queues), then argmin together (pipe idle).
// Fix: 128-thr blocks (2 waves x 64 rows), CT=32 (16KB tile, 32KB dbuf)
// -> 4 blocks/CU = 4 INDEPENDENT barrier domains, still 8 waves/CU.
// A block's 2 waves land on different SIMDs, so each SIMD's 2 resident
// waves belong to different domains -> natural antiphase on the matrix
// pipe. Per-wave work invariant (same MFMA/LDS/argmin); only sync
// topology changes. 32x32x16 shape, packed-key argmin, piece staging
// (1KB pieces, lane-matched, conflict-free), setprio on MFMA clusters.
__global__ __launch_bounds__(128, 2)
void vq_mfma(const float* __restrict__ z, const __bf16* __restrict__ cbb,
             const float* __restrict__ esq, unsigned* __restrict__ pK) {
    __shared__ __align__(16) __bf16 Bb[2][CT * DDIM];   // 2 x 16 KB

    const int rowbase  = (blockIdx.x >> 2) * RPB;
    const int kg       = blockIdx.x & 3;
    const int codebase = kg * CPB;

    const int tid = threadIdx.x;
    const int w = tid >> 6, l = tid & 63;       // wave = row-group (64 rows)
    const int la = l & 31, lh = l >> 5;
    const int loff = la * DDIM + lh * 8;        // lane offset in a 32-code group

    // ---- stage 0 loads first (overlap with A conversion below) ----
    // piece p (1 KB) = all 32 cols x k p*16..+15 (p = 0..15). Wave w stages
    // pieces w*8..w*8+7; lane l supplies col la, k-half lh -> LDS dest =
    // p*1024 + l*16 B (read-matched).
#pragma unroll
    for (int jj = 0; jj < 8; ++jj) {
        const int p = w * 8 + jj;
        __builtin_amdgcn_global_load_lds(
            (const __attribute__((address_space(1))) void*)
                (cbb + (size_t)codebase * DDIM + p * 16 + loff),
            (__attribute__((address_space(3))) void*)(&Bb[0][p * 512]),
            16, 0, 0);
    }

    // ---- A prologue: 64 rows x 256 k -> Af[2][16] bf16x8 (-2*z), 128 VGPRs ----
    bf16x8 Af[2][16];   // [row-frag s (32 rows)][k-chunk kc (16 k)]
    {
        const float* zp = z + (size_t)(rowbase + w * 64 + la) * DDIM + lh * 8;
#pragma unroll
        for (int s = 0; s < 2; ++s)
#pragma unroll
            for (int kc = 0; kc < 16; ++kc) {
                const float4 f0 = *(const float4*)(zp + s * 32 * DDIM + kc * 16);
                const float4 f1 = *(const float4*)(zp + s * 32 * DDIM + kc * 16 + 4);
                bf16x8 v;
                v[0] = (__bf16)(-2.f * f0.x); v[1] = (__bf16)(-2.f * f0.y);
                v[2] = (__bf16)(-2.f * f0.z); v[3] = (__bf16)(-2.f * f0.w);
                v[4] = (__bf16)(-2.f * f1.x); v[5] = (__bf16)(-2.f * f1.y);
                v[6] = (__bf16)(-2.f * f1.z); v[7] = (__bf16)(-2.f * f1.w);
                Af[s][kc] = v;
            }
    }

    // esq for stage 0 (ping-ponged; 1 reg per buffer: 32 cols/stage)
    float evc, evn;
    evc = esq[codebase + la];

    unsigned bestK[32];   // slot s*16+r: row (r&3)+8*(r>>2)+4*lh of frag s
#pragma unroll
    for (int s = 0; s < 32; ++s) bestK[s] = 0xFFFFFFFFu;

    __syncthreads();   // stage 0 staged (2-wave rendezvous)

    int buf = 0;
#pragma unroll 1
    for (int t = 0; t < TPB; ++t) {
        // issue next stage's 16 KB into the other buffer FIRST
        if (t + 1 < TPB) {
            const __bf16* base = cbb + (size_t)(codebase + (t + 1) * CT) * DDIM;
#pragma unroll
            for (int jj = 0; jj < 8; ++jj) {
                const int p = w * 8 + jj;
                __builtin_amdgcn_global_load_lds(
                    (const __attribute__((address_space(1))) void*)
                        (base + p * 16 + loff),
                    (__attribute__((address_space(3))) void*)(&Bb[buf ^ 1][p * 512]),
                    16, 0, 0);
            }
        }
        {   // prefetch next stage's esq (1 reg)
            const int tn = (t + 1) & (TPB - 1);
            evn = esq[codebase + tn * CT + la];
        }

        const __bf16* Bc = &Bb[buf][0];

        // ---- 32 cols -> one transient acc pair (2 row-frags) ----
        f32x16 acc0, acc1;
#pragma unroll
        for (int r = 0; r < 16; ++r) { acc0[r] = evc; acc1[r] = evc; }
        __builtin_amdgcn_s_setprio(1);
#pragma unroll
        for (int kc = 0; kc < 16; ++kc) {
            const bf16x8 b = *(const bf16x8*)(Bc + kc * 512 + l * 8);
            acc0 = __builtin_amdgcn_mfma_f32_32x32x16_bf16(Af[0][kc], b, acc0, 0, 0, 0);
            acc1 = __builtin_amdgcn_mfma_f32_32x32x16_bf16(Af[1][kc], b, acc1, 0, 0, 0);
        }
        __builtin_amdgcn_s_setprio(0);
        {   // immediate packed-key argmin (tiles ascend; strict <)
            const unsigned cA = (unsigned)(codebase + t * CT + la);
#pragma unroll
            for (int r = 0; r < 16; ++r) {
                const unsigned k0 = (__float_as_uint(acc0[r]) & 0xFFFFE000u) | cA;
                if (k0 < bestK[r])      bestK[r]      = k0;
                const unsigned k1 = (__float_as_uint(acc1[r]) & 0xFFFFE000u) | cA;
                if (k1 < bestK[16 + r]) bestK[16 + r] = k1;
            }
        }

        evc = evn;

        __syncthreads();   // 2-wave rendezvous; other 3 domains keep running
        buf ^= 1;
    }

    // cross-lane u32-min over the 32 col-lanes (masks 1..16 stay in-half)
#pragma unroll
    for (int s = 0; s < 32; ++s) {
#pragma unroll
        for (int m = 1; m < 32; m <<= 1) {
            const unsigned k2 = (unsigned)__shfl_xor((int)bestK[s], m);
            if (k2 < bestK[s]) bestK[s] = k2;
        }
    }
    // rows partition across waves: direct global writeout (lanes 0 and 32)
    if (la == 0) {
#pragma unroll
        for (int s = 0; s < 2; ++s)
#pragma unroll
            for (int r = 0; r < 16; ++r) {
                const int rl = w * 64 + s * 32 + (r & 3) + 8 * (r >> 2) + 4 * lh;
                pK[(size_t)(rowbase + rl) * KG + kg] = bestK[s * 16 + r];
            }
    }
}

// ---- kernel C: combine K-groups (u32 min), gather, STE out, loss partials ----
__global__ __launch_bounds__(256)
void vq_finalize(const float* __restrict__ z, const float* __restrict__ cb,
                 const unsigned* __restrict__ pK,
                 float* __restrict__ out, float* __restrict__ bsum) {
    __shared__ float sSum[4];
    __shared__ int   sIdx[4];
    const int tid = threadIdx.x;
    const int rw = tid >> 6, lane = tid & 63;
    const int row = blockIdx.x * 4 + rw;

    if (lane == 0) {  // u32 min over KG groups: value-min, smaller-index ties
        unsigned k = pK[row * KG];
#pragma unroll
        for (int q = 1; q < KG; ++q) {
            const unsigned k2 = pK[row * KG + q];
            if (k2 < k) k = k2;
        }
        sIdx[rw] = (int)(k & 0x1FFFu);
    }
    __syncthreads();
    const int idx = sIdx[rw];

    const float4 zv = *(const float4*)(z  + (size_t)row * DDIM + lane * 4);
    const float4 ev = *(const float4*)(cb + (size_t)idx * DDIM + lane * 4);
    float4 d, o;
    d.x = ev.x - zv.x; d.y = ev.y - zv.y; d.z = ev.z - zv.z; d.w = ev.w - zv.w;
    o.x = zv.x + d.x;  o.y = zv.y + d.y;  o.z = zv.z + d.z;  o.w = zv.w + d.w;
    *(float4*)(out + (size_t)row * DDIM + lane * 4) = o;

    float s = d.x * d.x + d.y * d.y + d.z * d.z + d.w * d.w;
    for (int off = 32; off > 0; off >>= 1) s += __shfl_down(s, off);
    if (lane == 0) sSum[rw] = s;
    __syncthreads();
    if (tid == 0) bsum[blockIdx.x] = sSum[0] + sSum[1] + sSum[2] + sSum[3];
}

// ---- kernel D: loss ----
__global__ __launch_bounds__(256)
void loss_final(const float* __restrict__ bsum, float* __restrict__ out) {
    __shared__ float red[4];
    const int tid = threadIdx.x;
    float s = 0.f;
    for (int i = tid; i < NROWS / 4; i += 256) s += bsum[i];
    for (int off = 32; off > 0; off >>= 1) s += __shfl_down(s, off);
    const int wv = tid >> 6, lane = tid & 63;
    if (lane == 0) red[wv] = s;
    __syncthreads();
    if (tid == 0) {
        const float tot = red[0] + red[1] + red[2] + red[3];
        out[(size_t)NROWS * DDIM] = tot * (1.25f / (float)((size_t)NROWS * DDIM));
    }
}

extern "C" void kernel_launch(void* const* d_in, const int* in_sizes, int n_in,
                              void* d_out, int out_size, void* d_ws, size_t ws_size,
                              hipStream_t stream) {
    const float* z  = (const float*)d_in[0];
    const float* cb = (const float*)d_in[1];
    float* out = (float*)d_out;

    // bf16 codebook staged at head of d_out (4 MB; consumed by vq_mfma
    // before vq_finalize overwrites the region)
    __bf16* cbf = (__bf16*)d_out;

    // workspace carve (~600 KB)
    float*    esq  = (float*)d_ws;               // 8192
    unsigned* pK   = (unsigned*)(esq + NCODES);  // 32768*4
    float*    bsum = (float*)(pK + NROWS * KG);  // 8192

    cvt_cb<<<NCODES * DDIM / 8 / 256, 256, 0, stream>>>(cb, cbf, esq);
    vq_mfma<<<(NROWS / RPB) * KG, 128, 0, stream>>>(z, cbf, esq, pK);
    vq_finalize<<<NROWS / 4, 256, 0, stream>>>(z, cb, pK, out, bsum);
    loss_final<<<1, 256, 0, stream>>>(bsum, out);
}

// Round 11
// 232.259 us; speedup vs baseline: 1.0810x; 1.0810x over previous
//
#include <hip/hip_runtime.h>
#include <cfloat>

#define NROWS  32768
#define NCODES 8192
#define DDIM   256
#define KG     4                 // code-split; grid = 128 row-tiles * 4 = 512 blocks
#define CPB    (NCODES / KG)     // 2048 codes per block
#define CT     64                // codes per stage (32 KB tile), double-buffered
#define TPB    (CPB / CT)        // 32 stages per block
#define RPB    256               // rows per block (4 waves x 64 rows)

typedef __attribute__((ext_vector_type(8)))  __bf16 bf16x8;
typedef __attribute__((ext_vector_type(16))) float  f32x16;

// ---- kernel A: codebook fp32 -> bf16 + fused esq (+1.0 bias for key-packing) ----
// esq' = ||e||^2 + 1 puts MFMA score s = esq' - 2 z.e in ~[0.4, 1.7]:
// strictly positive floats compare monotonically as u32 -> packed
// (score|index) argmin key in kernel B.
__global__ __launch_bounds__(256)
void cvt_cb(const float* __restrict__ cb, __bf16* __restrict__ cbb,
            float* __restrict__ esq) {
    const size_t i = (size_t)(blockIdx.x * 256 + threadIdx.x) * 8;
    const float4 f0 = *(const float4*)(cb + i);
    const float4 f1 = *(const float4*)(cb + i + 4);
    bf16x8 v;
    v[0] = (__bf16)f0.x; v[1] = (__bf16)f0.y; v[2] = (__bf16)f0.z; v[3] = (__bf16)f0.w;
    v[4] = (__bf16)f1.x; v[5] = (__bf16)f1.y; v[6] = (__bf16)f1.z; v[7] = (__bf16)f1.w;
    *(bf16x8*)(cbb + i) = v;
    float s = f0.x * f0.x + f0.y * f0.y + f0.z * f0.z + f0.w * f0.w
            + f1.x * f1.x + f1.y * f1.y + f1.z * f1.z + f1.w * f1.w;
    for (int o = 16; o > 0; o >>= 1) s += __shfl_down(s, o, 32);
    if ((threadIdx.x & 31) == 0) esq[i >> 8] = s + 1.0f;
}

// ---- kernel B: fused 64-col stage, 4 acc chains, argmin after barrier ----
// Post-mortem R10: 2-wave domains regressed (175us) -- per-barrier fixed
// cost ~3k cyc is ROUGHLY CONSTANT, so halving compute-per-barrier loses.
// R9 idle theory (a): each stage = two dependent sub-phases (MFMA-half ->
// argmin -> MFMA-half -> argmin) with only 2 acc chains -> two pipe-drain
// bubbles/stage. Fix on R9 geometry (256 thr, 4 waves x 64 rows, KG=4,
// 2 blocks/CU, CT=64 dbuf): ONE 64-col MFMA cluster with 4 independent
// chains (aA0,aA1,aB0,aB1; 64 transient regs), single argmin pass AFTER
// the barrier (s_barrier waits on memory cnts, not MFMA results -> waves
// rendezvous right after issue; argmin overlaps sibling block's MFMAs).
// Reg audit: Af 128 + acc 64 + bestK 32 + temps ~ 240 < 256 (R8 spill was
// 128+96+32+). Spill tripwire: WRITE_SIZE >10MB.
__global__ __launch_bounds__(256, 2)
void vq_mfma(const float* __restrict__ z, const __bf16* __restrict__ cbb,
             const float* __restrict__ esq, unsigned* __restrict__ pK) {
    __shared__ __align__(16) __bf16 Bb[2][CT * DDIM];   // 2 x 32 KB

    const int rowbase  = (blockIdx.x >> 2) * RPB;
    const int kg       = blockIdx.x & 3;
    const int codebase = kg * CPB;

    const int tid = threadIdx.x;
    const int w = tid >> 6, l = tid & 63;       // wave = row-group (64 rows)
    const int la = l & 31, lh = l >> 5;
    const int loff = la * DDIM + lh * 8;        // lane offset in a 32-code group

    // ---- stage 0 loads first (overlap with A conversion below) ----
    // piece p (1 KB) = cols (p>>4)*32..+31, k (p&15)*16..+15. Wave w stages
    // pieces w*8..w*8+7; lane l supplies col la, k-half lh -> LDS dest =
    // p*1024 + l*16 B (read-matched, conflict-free).
#pragma unroll
    for (int jj = 0; jj < 8; ++jj) {
        const int p = w * 8 + jj;
        const int fc = p >> 4, kc = p & 15;
        __builtin_amdgcn_global_load_lds(
            (const __attribute__((address_space(1))) void*)
                (cbb + (size_t)(codebase + fc * 32) * DDIM + kc * 16 + loff),
            (__attribute__((address_space(3))) void*)(&Bb[0][p * 512]),
            16, 0, 0);
    }

    // ---- A prologue: 64 rows x 256 k -> Af[2][16] bf16x8 (-2*z), 128 VGPRs ----
    bf16x8 Af[2][16];   // [row-frag s (32 rows)][k-chunk kc (16 k)]
    {
        const float* zp = z + (size_t)(rowbase + w * 64 + la) * DDIM + lh * 8;
#pragma unroll
        for (int s = 0; s < 2; ++s)
#pragma unroll
            for (int kc = 0; kc < 16; ++kc) {
                const float4 f0 = *(const float4*)(zp + s * 32 * DDIM + kc * 16);
                const float4 f1 = *(const float4*)(zp + s * 32 * DDIM + kc * 16 + 4);
                bf16x8 v;
                v[0] = (__bf16)(-2.f * f0.x); v[1] = (__bf16)(-2.f * f0.y);
                v[2] = (__bf16)(-2.f * f0.z); v[3] = (__bf16)(-2.f * f0.w);
                v[4] = (__bf16)(-2.f * f1.x); v[5] = (__bf16)(-2.f * f1.y);
                v[6] = (__bf16)(-2.f * f1.z); v[7] = (__bf16)(-2.f * f1.w);
                Af[s][kc] = v;
            }
    }

    // esq for stage 0 (ping-ponged; 2 regs per buffer)
    float evc[2], evn[2];
    evc[0] = esq[codebase + la];
    evc[1] = esq[codebase + 32 + la];

    unsigned bestK[32];   // slot s*16+r: row (r&3)+8*(r>>2)+4*lh of frag s
#pragma unroll
    for (int s = 0; s < 32; ++s) bestK[s] = 0xFFFFFFFFu;

    __syncthreads();   // stage 0 staged

    int buf = 0;
#pragma unroll 1
    for (int t = 0; t < TPB; ++t) {
        // issue next stage's 32 KB into the other buffer FIRST
        if (t + 1 < TPB) {
            const __bf16* base = cbb + (size_t)(codebase + (t + 1) * CT) * DDIM;
#pragma unroll
            for (int jj = 0; jj < 8; ++jj) {
                const int p = w * 8 + jj;
                const int fc = p >> 4, kc = p & 15;
                __builtin_amdgcn_global_load_lds(
                    (const __attribute__((address_space(1))) void*)
                        (base + (size_t)(fc * 32) * DDIM + kc * 16 + loff),
                    (__attribute__((address_space(3))) void*)(&Bb[buf ^ 1][p * 512]),
                    16, 0, 0);
            }
        }
        {   // prefetch next stage's esq (2 regs)
            const int tn = (t + 1) & (TPB - 1);
            evn[0] = esq[codebase + tn * CT + la];
            evn[1] = esq[codebase + tn * CT + 32 + la];
        }

        const __bf16* Bc = &Bb[buf][0];

        // ---- one fused 64-col cluster: 4 independent acc chains ----
        f32x16 aA0, aA1, aB0, aB1;
#pragma unroll
        for (int r = 0; r < 16; ++r) {
            aA0[r] = evc[0]; aA1[r] = evc[0];
            aB0[r] = evc[1]; aB1[r] = evc[1];
        }
        __builtin_amdgcn_s_setprio(1);
#pragma unroll
        for (int kc = 0; kc < 16; ++kc) {
            const bf16x8 b0 = *(const bf16x8*)(Bc + kc * 512 + l * 8);
            const bf16x8 b1 = *(const bf16x8*)(Bc + (16 + kc) * 512 + l * 8);
            aA0 = __builtin_amdgcn_mfma_f32_32x32x16_bf16(Af[0][kc], b0, aA0, 0, 0, 0);
            aA1 = __builtin_amdgcn_mfma_f32_32x32x16_bf16(Af[1][kc], b0, aA1, 0, 0, 0);
            aB0 = __builtin_amdgcn_mfma_f32_32x32x16_bf16(Af[0][kc], b1, aB0, 0, 0, 0);
            aB1 = __builtin_amdgcn_mfma_f32_32x32x16_bf16(Af[1][kc], b1, aB1, 0, 0, 0);
        }
        __builtin_amdgcn_s_setprio(0);

        // barrier BEFORE argmin: s_barrier only drains memory counters, so
        // waves rendezvous right after MFMA issue; the VALU argmin below
        // overlaps the sibling block's MFMA phase.
        __syncthreads();

        {   // single packed-key argmin pass (cols ascend; strict <)
            const unsigned cA = (unsigned)(codebase + t * CT + la);
            const unsigned cB = cA + 32;
#pragma unroll
            for (int r = 0; r < 16; ++r) {
                const unsigned kA0 = (__float_as_uint(aA0[r]) & 0xFFFFE000u) | cA;
                const unsigned kB0 = (__float_as_uint(aB0[r]) & 0xFFFFE000u) | cB;
                const unsigned m0 = kA0 < kB0 ? kA0 : kB0;
                if (m0 < bestK[r]) bestK[r] = m0;
                const unsigned kA1 = (__float_as_uint(aA1[r]) & 0xFFFFE000u) | cA;
                const unsigned kB1 = (__float_as_uint(aB1[r]) & 0xFFFFE000u) | cB;
                const unsigned m1 = kA1 < kB1 ? kA1 : kB1;
                if (m1 < bestK[16 + r]) bestK[16 + r] = m1;
            }
        }

        evc[0] = evn[0]; evc[1] = evn[1];
        buf ^= 1;
    }

    // cross-lane u32-min over the 32 col-lanes (masks 1..16 stay in-half)
#pragma unroll
    for (int s = 0; s < 32; ++s) {
#pragma unroll
        for (int m = 1; m < 32; m <<= 1) {
            const unsigned k2 = (unsigned)__shfl_xor((int)bestK[s], m);
            if (k2 < bestK[s]) bestK[s] = k2;
        }
    }
    // rows partition across waves: direct global writeout (lanes 0 and 32)
    if (la == 0) {
#pragma unroll
        for (int s = 0; s < 2; ++s)
#pragma unroll
            for (int r = 0; r < 16; ++r) {
                const int rl = w * 64 + s * 32 + (r & 3) + 8 * (r >> 2) + 4 * lh;
                pK[(size_t)(rowbase + rl) * KG + kg] = bestK[s * 16 + r];
            }
    }
}

// ---- kernel C: combine K-groups (u32 min), gather, STE out, loss partials ----
__global__ __launch_bounds__(256)
void vq_finalize(const float* __restrict__ z, const float* __restrict__ cb,
                 const unsigned* __restrict__ pK,
                 float* __restrict__ out, float* __restrict__ bsum) {
    __shared__ float sSum[4];
    __shared__ int   sIdx[4];
    const int tid = threadIdx.x;
    const int rw = tid >> 6, lane = tid & 63;
    const int row = blockIdx.x * 4 + rw;

    if (lane == 0) {  // u32 min over KG groups: value-min, smaller-index ties
        unsigned k = pK[row * KG];
#pragma unroll
        for (int q = 1; q < KG; ++q) {
            const unsigned k2 = pK[row * KG + q];
            if (k2 < k) k = k2;
        }
        sIdx[rw] = (int)(k & 0x1FFFu);
    }
    __syncthreads();
    const int idx = sIdx[rw];

    const float4 zv = *(const float4*)(z  + (size_t)row * DDIM + lane * 4);
    const float4 ev = *(const float4*)(cb + (size_t)idx * DDIM + lane * 4);
    float4 d, o;
    d.x = ev.x - zv.x; d.y = ev.y - zv.y; d.z = ev.z - zv.z; d.w = ev.w - zv.w;
    o.x = zv.x + d.x;  o.y = zv.y + d.y;  o.z = zv.z + d.z;  o.w = zv.w + d.w;
    *(float4*)(out + (size_t)row * DDIM + lane * 4) = o;

    float s = d.x * d.x + d.y * d.y + d.z * d.z + d.w * d.w;
    for (int off = 32; off > 0; off >>= 1) s += __shfl_down(s, off);
    if (lane == 0) sSum[rw] = s;
    __syncthreads();
    if (tid == 0) bsum[blockIdx.x] = sSum[0] + sSum[1] + sSum[2] + sSum[3];
}

// ---- kernel D: loss ----
__global__ __launch_bounds__(256)
void loss_final(const float* __restrict__ bsum, float* __restrict__ out) {
    __shared__ float red[4];
    const int tid = threadIdx.x;
    float s = 0.f;
    for (int i = tid; i < NROWS / 4; i += 256) s += bsum[i];
    for (int off = 32; off > 0; off >>= 1) s += __shfl_down(s, off);
    const int wv = tid >> 6, lane = tid & 63;
    if (lane == 0) red[wv] = s;
    __syncthreads();
    if (tid == 0) {
        const float tot = red[0] + red[1] + red[2] + red[3];
        out[(size_t)NROWS * DDIM] = tot * (1.25f / (float)((size_t)NROWS * DDIM));
    }
}

extern "C" void kernel_launch(void* const* d_in, const int* in_sizes, int n_in,
                              void* d_out, int out_size, void* d_ws, size_t ws_size,
                              hipStream_t stream) {
    const float* z  = (const float*)d_in[0];
    const float* cb = (const float*)d_in[1];
    float* out = (float*)d_out;

    // bf16 codebook staged at head of d_out (4 MB; consumed by vq_mfma
    // before vq_finalize overwrites the region)
    __bf16* cbf = (__bf16*)d_out;

    // workspace carve (~600 KB)
    float*    esq  = (float*)d_ws;               // 8192
    unsigned* pK   = (unsigned*)(esq + NCODES);  // 32768*4
    float*    bsum = (float*)(pK + NROWS * KG);  // 8192

    cvt_cb<<<NCODES * DDIM / 8 / 256, 256, 0, stream>>>(cb, cbf, esq);
    vq_mfma<<<(NROWS / RPB) * KG, 256, 0, stream>>>(z, cbf, esq, pK);
    vq_finalize<<<NROWS / 4, 256, 0, stream>>>(z, cb, pK, out, bsum);
    loss_final<<<1, 256, 0, stream>>>(bsum, out);
}